// Round 2
// baseline (56.172 us; speedup 1.0000x reference)
//
#include <hip/hip_runtime.h>

#define Bt 32768
#define Dt 64
#define St 16
#define Ht 128
#define At 17

typedef __attribute__((ext_vector_type(8))) short bf16x8;
typedef __attribute__((ext_vector_type(4))) float f32x4;

// ---- workspace layout (bytes) ----
#define CNT_OFF   0          // int[16]
#define PERM_OFF  128        // u16 [S][B]  (1 MiB)
#define WB_OFF    1049600    // bf16 transposed weight images [n][k], NO swizzle
#define OA1 0        // Wa1^T: 128 rows x 128B (K=64)
#define OA2 16384    // Wa2^T: 128 rows x 256B (K=128)
#define OA3 49152    // Wa3^T: 32-row region, rows >=17 unused garbage
#define OC1 57344    // Wc1^T
#define OC2 73728    // Wc2^T
#define SKB 106496   // per-skill stride

__device__ __forceinline__ unsigned short f2bf(float f) {
  union { float f; unsigned u; } v; v.f = f;
  unsigned r = v.u + 0x7FFFu + ((v.u >> 16) & 1u);  // RNE
  return (unsigned short)(r >> 16);
}

__device__ __forceinline__ float fast_tanh(float x) {
  float t = __expf(2.0f * x);                 // inf-safe: t=inf -> 1, t=0 -> -1
  return 1.0f - __fdividef(2.0f, t + 1.0f);
}

__device__ __forceinline__ f32x4 MFMA(bf16x8 a, bf16x8 b, f32x4 c) {
  return __builtin_amdgcn_mfma_f32_16x16x32_bf16(a, b, c, 0, 0, 0);
}

// intra-wave LDS RAW fence (hbuf is wave-private; no __syncthreads needed)
#define LGKM0() asm volatile("s_waitcnt lgkmcnt(0)" ::: "memory")

// ---------- dispatch 2: fused bucket (blocks 80..207) + weight prep (blocks 0..79) ----------
__global__ __launch_bounds__(256) void k_fused(
    const int* __restrict__ sid, unsigned short* __restrict__ perm,
    int* __restrict__ cnt,
    const float* __restrict__ Wa1, const float* __restrict__ Wa2,
    const float* __restrict__ Wa3, const float* __restrict__ Wc1,
    const float* __restrict__ Wc2, char* __restrict__ G) {
  __shared__ __align__(16) char smem[32768];
  const int tid = threadIdx.x;
  const int bid = blockIdx.x;

  if (bid >= 80) {
    // ---- bucket role: scatter row ids into per-skill lists ----
    int* lc = (int*)smem;
    int* lb = lc + St;
    const int b = (bid - 80) * 256 + tid;
    if (tid < St) lc[tid] = 0;
    __syncthreads();
    const int s = sid[b];
    const int p = atomicAdd(&lc[s], 1);
    __syncthreads();
    if (tid < St) lb[tid] = atomicAdd(&cnt[tid], lc[tid]);
    __syncthreads();
    perm[s * Bt + lb[s] + p] = (unsigned short)b;
    return;
  }

  // ---- prep role: fp32 [k][n] -> bf16 [n][k] image, via LDS transpose ----
  const int s = bid / 5, m = bid % 5;
  char* Gs = G + s * SKB;

  if (m == 2) {  // Wa3: 128x17, small & irregular -> direct scatter
    const float* src = Wa3 + s * Ht * At;
    for (int e = tid; e < Ht * At; e += 256) {
      const int k = e / At, n = e - k * At;
      *(unsigned short*)(Gs + OA3 + n * 256 + 2 * k) = f2bf(src[e]);
    }
    return;
  }

  const float* src; int K, off;
  if (m == 0)      { src = Wa1 + s * Dt * Ht; K = 64;  off = OA1; }
  else if (m == 1) { src = Wa2 + s * Ht * Ht; K = 128; off = OA2; }
  else if (m == 3) { src = Wc1 + s * Dt * Ht; K = 64;  off = OC1; }
  else             { src = Wc2 + s * Ht * Ht; K = 128; off = OC2; }
  const int SB = 2 * K;                 // image row bytes
  const int lsb = (K == 128) ? 8 : 7;
  const int pm = (K == 128) ? 15 : 7;   // prep-local XOR swizzle mask (bank spread)

  unsigned short* lds = (unsigned short*)smem;
  // phase 1: coalesced f32x4 reads along n; transposed, P_n-swizzled LDS writes
  for (int it = 0; it < K / 8; ++it) {
    const int f = (it * 256 + tid) * 4;  // flat float index, src is [k][128]
    const int k = f >> 7, n0 = f & 127;
    const f32x4 v = *(const f32x4*)(src + f);
#pragma unroll
    for (int j = 0; j < 4; ++j) {
      const int n = n0 + j;
      const int byte = n * SB + ((2 * k) ^ (((n >> 2) & pm) << 4));
      lds[byte >> 1] = f2bf(v[j]);
    }
  }
  __syncthreads();
  // phase 2: un-swizzled readout (2-way max), fully coalesced 8B global writes
  const int nbytes = 128 * SB;
  for (int it = 0; it < nbytes / 2048; ++it) {
    const int q = (it * 256 + tid) * 8;
    const int n = q >> lsb, r = q & (SB - 1);
    const unsigned long long v8 =
        *(const unsigned long long*)(smem + n * SB + (r ^ (((n >> 2) & pm) << 4)));
    *(unsigned long long*)(Gs + off + q) = v8;
  }
}

// ---------- dispatch 3: fused per-skill actor+critic MLP, barrier-free ----------
__global__ __launch_bounds__(256, 3) void k_main(
    const float* __restrict__ obs,
    const float* __restrict__ ba1, const float* __restrict__ ba2,
    const float* __restrict__ ba3, const float* __restrict__ bc1,
    const float* __restrict__ bc2, const float* __restrict__ Wc3,
    const float* __restrict__ bc3,
    const int* __restrict__ cnt, const unsigned short* __restrict__ perm,
    const char* __restrict__ G, float* __restrict__ out) {
  __shared__ char hbuf[16384];   // 64 rows x 256B bf16 activations, wave-private rows

  const int s = blockIdx.y;
  const int count = cnt[s];
  const int base = blockIdx.x * 64;
  if (base >= count) return;

  const int tid = threadIdx.x;
  const int wave = tid >> 6, lane = tid & 63;
  const int lr = lane & 15, lg = lane >> 4;
  const int cm1 = count - 1 - base;     // clamp limit (tile-local); >= 0 here

  const unsigned short* ps = perm + s * Bt + base;
  const int myrow = ps[min(wave * 16 + lr, cm1)];   // clamp: tail entries are poison
  int orow[4]; bool oval[4];
#pragma unroll
  for (int i = 0; i < 4; ++i) {
    const int r = wave * 16 + lg * 4 + i;
    oval[i] = (r <= cm1);
    orow[i] = ps[min(r, cm1)];
  }

  // layer-1 A fragments from gathered obs rows (shared by actor & critic)
  const float* ap = obs + myrow * Dt + lg * 8;
  const f32x4 x0 = *(const f32x4*)(ap);
  const f32x4 x1 = *(const f32x4*)(ap + 4);
  const f32x4 x2 = *(const f32x4*)(ap + 32);
  const f32x4 x3 = *(const f32x4*)(ap + 36);
  bf16x8 a0, a1;
#pragma unroll
  for (int j = 0; j < 4; ++j) {
    a0[j] = (short)f2bf(x0[j]); a0[4 + j] = (short)f2bf(x1[j]);
    a1[j] = (short)f2bf(x2[j]); a1[4 + j] = (short)f2bf(x3[j]);
  }

  const char* Gs = G + s * SKB;
  const int hr = wave * 16 + lr;          // own LDS row for A-frag reads
  const int hsw = (hr & 7) << 4;
  const char* hrow = hbuf + hr * 256;

  // ================= actor layer 1 =================
#pragma unroll
  for (int nt = 0; nt < 8; ++nt) {
    const int n = nt * 16 + lr;
    const char* wrow = Gs + OA1 + n * 128;          // B-frags direct from L2
    const bf16x8 b0 = *(const bf16x8*)(wrow + lg * 16);
    const bf16x8 b1 = *(const bf16x8*)(wrow + 64 + lg * 16);
    f32x4 acc = {0.f, 0.f, 0.f, 0.f};
    acc = MFMA(a0, b0, acc);
    acc = MFMA(a1, b1, acc);
    const float bias = ba1[s * Ht + n];
#pragma unroll
    for (int i = 0; i < 4; ++i) {
      const int row = wave * 16 + lg * 4 + i;   // C/D: col=lane&15, row=(lane>>4)*4+i
      *(unsigned short*)(hbuf + row * 256 + ((2 * n) ^ ((row & 7) << 4))) =
          f2bf(fast_tanh(acc[i] + bias));
    }
  }
  LGKM0();

  // ================= actor layer 2 =================
  {
    const bf16x8 A0 = *(const bf16x8*)(hrow + ((0   + lg * 16) ^ hsw));
    const bf16x8 A1 = *(const bf16x8*)(hrow + ((64  + lg * 16) ^ hsw));
    const bf16x8 A2 = *(const bf16x8*)(hrow + ((128 + lg * 16) ^ hsw));
    const bf16x8 A3 = *(const bf16x8*)(hrow + ((192 + lg * 16) ^ hsw));
#pragma unroll
    for (int nt = 0; nt < 8; ++nt) {
      const int n = nt * 16 + lr;
      const char* wrow = Gs + OA2 + n * 256;
      f32x4 acc = {0.f, 0.f, 0.f, 0.f};
      acc = MFMA(A0, *(const bf16x8*)(wrow + lg * 16), acc);
      acc = MFMA(A1, *(const bf16x8*)(wrow + 64 + lg * 16), acc);
      acc = MFMA(A2, *(const bf16x8*)(wrow + 128 + lg * 16), acc);
      acc = MFMA(A3, *(const bf16x8*)(wrow + 192 + lg * 16), acc);
      const float bias = ba2[s * Ht + n];
#pragma unroll
      for (int i = 0; i < 4; ++i) {
        const int row = wave * 16 + lg * 4 + i;   // own rows only: race-free
        *(unsigned short*)(hbuf + row * 256 + ((2 * n) ^ ((row & 7) << 4))) =
            f2bf(fast_tanh(acc[i] + bias));
      }
    }
  }
  LGKM0();

  // ================= actor layer 3 -> logits =================
  {
    const bf16x8 A0 = *(const bf16x8*)(hrow + ((0   + lg * 16) ^ hsw));
    const bf16x8 A1 = *(const bf16x8*)(hrow + ((64  + lg * 16) ^ hsw));
    const bf16x8 A2 = *(const bf16x8*)(hrow + ((128 + lg * 16) ^ hsw));
    const bf16x8 A3 = *(const bf16x8*)(hrow + ((192 + lg * 16) ^ hsw));
#pragma unroll
    for (int nt = 0; nt < 2; ++nt) {
      const int n = nt * 16 + lr;    // cols 17..31 read garbage weights; per-lane
      const char* wrow = Gs + OA3 + n * 256;   // isolated in discarded lanes
      f32x4 acc = {0.f, 0.f, 0.f, 0.f};
      acc = MFMA(A0, *(const bf16x8*)(wrow + lg * 16), acc);
      acc = MFMA(A1, *(const bf16x8*)(wrow + 64 + lg * 16), acc);
      acc = MFMA(A2, *(const bf16x8*)(wrow + 128 + lg * 16), acc);
      acc = MFMA(A3, *(const bf16x8*)(wrow + 192 + lg * 16), acc);
      if (n < At) {
        const float bias = ba3[s * At + n];
#pragma unroll
        for (int i = 0; i < 4; ++i) {
          if (oval[i]) out[orow[i] * At + n] = acc[i] + bias;
        }
      }
    }
  }

  // ================= critic layer 1 (a0,a1 still live) =================
#pragma unroll
  for (int nt = 0; nt < 8; ++nt) {
    const int n = nt * 16 + lr;
    const char* wrow = Gs + OC1 + n * 128;
    const bf16x8 b0 = *(const bf16x8*)(wrow + lg * 16);
    const bf16x8 b1 = *(const bf16x8*)(wrow + 64 + lg * 16);
    f32x4 acc = {0.f, 0.f, 0.f, 0.f};
    acc = MFMA(a0, b0, acc);
    acc = MFMA(a1, b1, acc);
    const float bias = bc1[s * Ht + n];
#pragma unroll
    for (int i = 0; i < 4; ++i) {
      const int row = wave * 16 + lg * 4 + i;
      *(unsigned short*)(hbuf + row * 256 + ((2 * n) ^ ((row & 7) << 4))) =
          f2bf(fast_tanh(acc[i] + bias));
    }
  }
  LGKM0();

  // ================= critic layer 2 + value (in-register epilogue) =================
  {
    const bf16x8 A0 = *(const bf16x8*)(hrow + ((0   + lg * 16) ^ hsw));
    const bf16x8 A1 = *(const bf16x8*)(hrow + ((64  + lg * 16) ^ hsw));
    const bf16x8 A2 = *(const bf16x8*)(hrow + ((128 + lg * 16) ^ hsw));
    const bf16x8 A3 = *(const bf16x8*)(hrow + ((192 + lg * 16) ^ hsw));
    float vp0 = 0.f, vp1 = 0.f, vp2 = 0.f, vp3 = 0.f;
#pragma unroll
    for (int nt = 0; nt < 8; ++nt) {
      const int n = nt * 16 + lr;
      const char* wrow = Gs + OC2 + n * 256;
      f32x4 acc = {0.f, 0.f, 0.f, 0.f};
      acc = MFMA(A0, *(const bf16x8*)(wrow + lg * 16), acc);
      acc = MFMA(A1, *(const bf16x8*)(wrow + 64 + lg * 16), acc);
      acc = MFMA(A2, *(const bf16x8*)(wrow + 128 + lg * 16), acc);
      acc = MFMA(A3, *(const bf16x8*)(wrow + 192 + lg * 16), acc);
      const float bias = bc2[s * Ht + n];
      const float w3 = Wc3[s * Ht + n];
      vp0 += fast_tanh(acc[0] + bias) * w3;
      vp1 += fast_tanh(acc[1] + bias) * w3;
      vp2 += fast_tanh(acc[2] + bias) * w3;
      vp3 += fast_tanh(acc[3] + bias) * w3;
    }
#pragma unroll
    for (int d = 1; d < 16; d <<= 1) {   // reduce over the 16 cols held per lane group
      vp0 += __shfl_xor(vp0, d);
      vp1 += __shfl_xor(vp1, d);
      vp2 += __shfl_xor(vp2, d);
      vp3 += __shfl_xor(vp3, d);
    }
    if (lr == 0) {
      const float b3 = bc3[s];
      if (oval[0]) out[Bt * At + orow[0]] = vp0 + b3;
      if (oval[1]) out[Bt * At + orow[1]] = vp1 + b3;
      if (oval[2]) out[Bt * At + orow[2]] = vp2 + b3;
      if (oval[3]) out[Bt * At + orow[3]] = vp3 + b3;
    }
  }
}

extern "C" void kernel_launch(void* const* d_in, const int* in_sizes, int n_in,
                              void* d_out, int out_size, void* d_ws, size_t ws_size,
                              hipStream_t stream) {
  const float* obs = (const float*)d_in[0];
  const int* sid   = (const int*)d_in[1];
  const float* Wa1 = (const float*)d_in[2];
  const float* ba1 = (const float*)d_in[3];
  const float* Wa2 = (const float*)d_in[4];
  const float* ba2 = (const float*)d_in[5];
  const float* Wa3 = (const float*)d_in[6];
  const float* ba3 = (const float*)d_in[7];
  const float* Wc1 = (const float*)d_in[8];
  const float* bc1 = (const float*)d_in[9];
  const float* Wc2 = (const float*)d_in[10];
  const float* bc2 = (const float*)d_in[11];
  const float* Wc3 = (const float*)d_in[12];
  const float* bc3 = (const float*)d_in[13];
  float* out = (float*)d_out;
  char* ws = (char*)d_ws;

  int* cnt = (int*)(ws + CNT_OFF);
  unsigned short* perm = (unsigned short*)(ws + PERM_OFF);
  char* G = ws + WB_OFF;

  hipMemsetAsync(cnt, 0, St * sizeof(int), stream);
  k_fused<<<dim3(208), dim3(256), 0, stream>>>(sid, perm, cnt, Wa1, Wa2, Wa3, Wc1, Wc2, G);
  k_main<<<dim3(Bt / 64, St), dim3(256), 0, stream>>>(
      obs, ba1, ba2, ba3, bc1, bc2, Wc3, bc3, cnt, perm, G, out);
}